// Round 6
// baseline (811.390 us; speedup 1.0000x reference)
//
#include <hip/hip_runtime.h>
#include <hip/hip_bf16.h>

typedef __bf16 bf16;
typedef bf16 bf16x4 __attribute__((ext_vector_type(4)));
typedef bf16 bf16x8 __attribute__((ext_vector_type(8)));
typedef float f32x4 __attribute__((ext_vector_type(4)));

#define MFMA16(a, b, c) __builtin_amdgcn_mfma_f32_16x16x32_bf16((a), (b), (c), 0, 0, 0)

constexpr float kScale = 0.17677669529663687f;  // 1/sqrt(32)

// ---- workspace offsets (bytes) ----
constexpr int WQKV_OFF = 0;        // bf16[768*256]
constexpr int WPROJ_OFF = 393216;  // bf16[256*256]
constexpr int BIAS_OFF = 524288;   // f32[8][49 m][49 n]  (transposed bias)
constexpr int BQKV_OFF = 601120;   // f32[768]

// ---- LDS layout (bytes) ----
// region A: x staging bf16 [32 cc][50 n][8] = 25600 B; later proj f32 half [49][128] = 25088 B
// region B: attn-out bf16 [32 cc][50 n][8] = 25600 B
// + 256 B guard for benign OOB tile reads
constexpr int A_OFF = 0;
constexpr int B_OFF = 25600;
constexpr int QS = 400;  // row-chunk stride in elems (50*8)
constexpr int LDS_BYTES = 51456;

__global__ void prep_kernel(const float* __restrict__ w_qkv, const float* __restrict__ b_qkv,
                            const float* __restrict__ w_proj, const float* __restrict__ bias_table,
                            const int* __restrict__ rel_index, char* __restrict__ ws) {
  int i = blockIdx.x * 256 + threadIdx.x;
  bf16* wqkvb = (bf16*)(ws + WQKV_OFF);
  bf16* wprojb = (bf16*)(ws + WPROJ_OFF);
  float* biasx = (float*)(ws + BIAS_OFF);
  float* bqs = (float*)(ws + BQKV_OFF);
  if (i < 196608) {
    float v = w_qkv[i];
    if (i < 65536) v *= kScale;  // q rows (o<256): fold scale
    wqkvb[i] = (bf16)v;
  } else if (i < 262144) {
    int j = i - 196608;
    wprojb[j] = (bf16)w_proj[j];
  } else if (i < 281352) {
    int j = i - 262144;  // 8*2401, layout [h][m][n]
    int h = j / 2401, nm = j - h * 2401;
    int mm = nm / 49, nn = nm - mm * 49;
    biasx[j] = bias_table[rel_index[nn * 49 + mm] * 8 + h];  // bias[h][nn][mm]
  } else if (i < 282120) {
    int j = i - 281352;
    bqs[j] = b_qkv[j] * (j < 256 ? kScale : 1.0f);
  }
}

__global__ __launch_bounds__(256, 3) void attn_kernel(
    const float* __restrict__ x, const float* __restrict__ mask, const float* __restrict__ b_proj,
    const char* __restrict__ ws, float* __restrict__ out) {
  extern __shared__ char smem[];
  bf16* xb = (bf16*)(smem + A_OFF);
  bf16* ao = (bf16*)(smem + B_OFF);
  float* outf = (float*)(smem + A_OFF);  // proj staging overlays xb

  const bf16* wqkvb = (const bf16*)(ws + WQKV_OFF);
  const bf16* wprojb = (const bf16*)(ws + WPROJ_OFF);
  const float* biasx = (const float*)(ws + BIAS_OFF);
  const float* bqs = (const float*)(ws + BQKV_OFF);

  const int tid = threadIdx.x;
  const int w = blockIdx.x;
  const int lane = tid & 63;
  const int wave = tid >> 6;  // 0..3
  const int g = lane >> 4;    // 16-lane group
  const int c = lane & 15;

  const float* xw = x + (size_t)w * 12544;

  // ---- stage x -> xb bf16, [cc][n<49][8] ----
#pragma unroll
  for (int it = 0; it < 13; ++it) {
    int idx = it * 256 + tid;
    if (idx < 3136) {
      int n = idx >> 6, c4 = (idx & 63) << 2;
      float4 v = ((const float4*)xw)[idx];
      bf16x4 b4;
      b4[0] = (bf16)v.x; b4[1] = (bf16)v.y; b4[2] = (bf16)v.z; b4[3] = (bf16)v.w;
      *(bf16x4*)(xb + ((c4 >> 3) * QS + n * 8 + (c4 & 7))) = b4;
    }
  }
  __syncthreads();

  const float* mk = mask + (size_t)w * 2401;
  const int h0 = wave * 2;

  for (int hh = 0; hh < 2; ++hh) {
    const int h = h0 + hh;

    // ---- Q,K fragments: register GEMM1 (2 tiles each) + shuffle transpose ----
    bf16x8 qa[4], kb[4];
#pragma unroll
    for (int qksel = 0; qksel < 2; ++qksel) {
      const int obase = qksel * 256 + h * 32;
      f32x4 acc2[2][4] = {};
#pragma unroll
      for (int tf = 0; tf < 2; ++tf) {
        const bf16* abw = wqkvb + (obase + tf * 16 + c) * 256 + g * 8;
        bf16x8 afr[8];
#pragma unroll
        for (int ks = 0; ks < 8; ++ks) afr[ks] = *(const bf16x8*)(abw + ks * 32);
#pragma unroll
        for (int ks = 0; ks < 8; ++ks) {
          const bf16* bb = xb + (ks * 4 + g) * QS + c * 8;
#pragma unroll
          for (int nt = 0; nt < 4; ++nt) {
            bf16x8 bfr = *(const bf16x8*)(bb + nt * 128);
            acc2[tf][nt] = MFMA16(afr[ks], bfr, acc2[tf][nt]);
          }
        }
#pragma unroll
        for (int i = 0; i < 4; ++i) {
          float bq = bqs[obase + tf * 16 + g * 4 + i];
#pragma unroll
          for (int nt = 0; nt < 4; ++nt) acc2[tf][nt][i] += bq;
        }
      }
      // D[o][n] -> frag[rt][j] = T[n=rt*16+c][d=g*8+j]
      const int base = (g & 1) * 32 + c;
#pragma unroll
      for (int rt = 0; rt < 4; ++rt) {
        float e[8];
#pragma unroll
        for (int i = 0; i < 4; ++i) {
          float a0 = __shfl(acc2[0][rt][i], base);
          float a1 = __shfl(acc2[0][rt][i], base + 16);
          float b0 = __shfl(acc2[1][rt][i], base);
          float b1 = __shfl(acc2[1][rt][i], base + 16);
          e[i] = (g < 2) ? a0 : b0;
          e[i + 4] = (g < 2) ? a1 : b1;
        }
        bf16x8 f;
#pragma unroll
        for (int j = 0; j < 8; ++j) f[j] = (bf16)e[j];
        if (qksel == 0) qa[rt] = f; else kb[rt] = f;
      }
    }

    // ---- V fragments: register GEMM2 + shuffle transpose ----
    bf16x8 va[2][2];  // [dt][ks]
#pragma unroll
    for (int dt = 0; dt < 2; ++dt) {
      const int ct = wave * 4 + hh * 2 + dt;
      const int o = 512 + ct * 16 + c;
      const bf16* bbw = wqkvb + o * 256 + g * 8;
      bf16x8 bfr[8];
#pragma unroll
      for (int ks = 0; ks < 8; ++ks) bfr[ks] = *(const bf16x8*)(bbw + ks * 32);
      f32x4 acc[4] = {};
#pragma unroll
      for (int ks = 0; ks < 8; ++ks) {
        const bf16* abL = xb + (ks * 4 + g) * QS + c * 8;
#pragma unroll
        for (int mt = 0; mt < 4; ++mt) {
          bf16x8 afr = *(const bf16x8*)(abL + mt * 128);
          acc[mt] = MFMA16(afr, bfr[ks], acc[mt]);
        }
      }
      const float bv = bqs[o];
#pragma unroll
      for (int mt = 0; mt < 4; ++mt) {
        acc[mt][0] += bv; acc[mt][1] += bv; acc[mt][2] += bv; acc[mt][3] += bv;
      }
      const int base = (g & 1) * 32 + c;
#pragma unroll
      for (int ks = 0; ks < 2; ++ks) {
        float e[8];
#pragma unroll
        for (int i = 0; i < 4; ++i) {
          float xA = __shfl(acc[2 * ks][i], base);
          float yA = __shfl(acc[2 * ks + 1][i], base);
          float xB = __shfl(acc[2 * ks][i], base + 16);
          float yB = __shfl(acc[2 * ks + 1][i], base + 16);
          e[i] = (g < 2) ? xA : yA;
          e[i + 4] = (g < 2) ? xB : yB;
        }
        bf16x8 f;
#pragma unroll
        for (int j = 0; j < 8; ++j) {
          int m = ks * 32 + g * 8 + j;
          f[j] = (m < 49) ? (bf16)e[j] : (bf16)0.f;
        }
        va[dt][ks] = f;
      }
    }

    // ---- attention: per column-tile, fused S^T -> softmax -> PV ----
    const float* bhT = biasx + h * 2401;
    f32x4 oacc[2][4] = {};
#pragma unroll
    for (int nt = 0; nt < 4; ++nt) {
      f32x4 z = {};
      f32x4 sc[4];
#pragma unroll
      for (int mt = 0; mt < 4; ++mt) sc[mt] = MFMA16(kb[mt], qa[nt], z);
      const int n = nt * 16 + c;
      const int nc = n > 48 ? 48 : n;
      const bool nok = (n < 49);
      float vals[4][4];
#pragma unroll
      for (int mt = 0; mt < 4; ++mt)
#pragma unroll
        for (int i = 0; i < 4; ++i) {
          int m = mt * 16 + g * 4 + i;
          int mc2 = m > 48 ? 48 : m;
          float bv = bhT[mc2 * 49 + nc];
          float mv = mk[nc * 49 + mc2];
          vals[mt][i] = (nok && m < 49) ? (sc[mt][i] + bv + mv) : -1e30f;
        }
      float mx = vals[0][0];
#pragma unroll
      for (int mt = 0; mt < 4; ++mt)
#pragma unroll
        for (int i = 0; i < 4; ++i) mx = fmaxf(mx, vals[mt][i]);
      mx = fmaxf(mx, __shfl_xor(mx, 16));
      mx = fmaxf(mx, __shfl_xor(mx, 32));
      float p_[4][4];
      float sum = 0.f;
#pragma unroll
      for (int mt = 0; mt < 4; ++mt)
#pragma unroll
        for (int i = 0; i < 4; ++i) {
          float pv = __expf(vals[mt][i] - mx);
          p_[mt][i] = pv;
          sum += pv;
        }
      sum += __shfl_xor(sum, 16);
      sum += __shfl_xor(sum, 32);
      float rinv = nok ? (1.0f / sum) : 0.0f;
#pragma unroll
      for (int mt = 0; mt < 4; ++mt)
#pragma unroll
        for (int i = 0; i < 4; ++i) p_[mt][i] *= rinv;

      // P^T fragment via register shuffle, then PV
#pragma unroll
      for (int ks = 0; ks < 2; ++ks) {
        float e[8];
#pragma unroll
        for (int j = 0; j < 8; ++j) {
          int src = ((g & 1) * 2 + (j >> 2)) * 16 + c;
          float vA = __shfl(p_[2 * ks][j & 3], src);
          float vB = __shfl(p_[2 * ks + 1][j & 3], src);
          e[j] = (g < 2) ? vA : vB;
        }
        bf16x8 f;
#pragma unroll
        for (int j = 0; j < 8; ++j) f[j] = (bf16)e[j];
#pragma unroll
        for (int dt = 0; dt < 2; ++dt) oacc[dt][nt] = MFMA16(va[dt][ks], f, oacc[dt][nt]);
      }
    }

    // ---- attn-out -> ao (region B; no ordering hazard) ----
#pragma unroll
    for (int dt = 0; dt < 2; ++dt) {
      int cb = h * 32 + dt * 16 + g * 4;
      int cc = cb >> 3, clow = cb & 7;
#pragma unroll
      for (int nt = 0; nt < 4; ++nt) {
        int n = nt * 16 + c;
        if (n < 49) {
          bf16x4 pk;
          pk[0] = (bf16)oacc[dt][nt][0]; pk[1] = (bf16)oacc[dt][nt][1];
          pk[2] = (bf16)oacc[dt][nt][2]; pk[3] = (bf16)oacc[dt][nt][3];
          *(bf16x4*)(ao + (cc * QS + n * 8 + clow)) = pk;
        }
      }
    }
  }
  __syncthreads();  // all attn-out written; xb (x content) dead

  // ---- proj in two co-halves, staged through region A, coalesced copy out ----
  float4* outw4 = (float4*)(out + (size_t)w * 12544);
  const float4* outf4 = (const float4*)outf;
#pragma unroll
  for (int half = 0; half < 2; ++half) {
#pragma unroll
    for (int tt = 0; tt < 2; ++tt) {
      const int ctl = wave * 2 + tt;  // 0..7
      const int ct = half * 8 + ctl;
      const bf16* bbw = wprojb + (ct * 16 + c) * 256 + g * 8;
      bf16x8 bfr[8];
#pragma unroll
      for (int ks = 0; ks < 8; ++ks) bfr[ks] = *(const bf16x8*)(bbw + ks * 32);
      f32x4 acc[4] = {};
#pragma unroll
      for (int ks = 0; ks < 8; ++ks) {
        const bf16* abL = ao + (ks * 4 + g) * QS + c * 8;
#pragma unroll
        for (int mt = 0; mt < 4; ++mt) {
          bf16x8 afr = *(const bf16x8*)(abL + mt * 128);
          acc[mt] = MFMA16(afr, bfr[ks], acc[mt]);
        }
      }
      float bp = b_proj[ct * 16 + c];
      const int q = ctl * 4 + (c >> 2);
      const int c3 = c & 3;
#pragma unroll
      for (int mt = 0; mt < 4; ++mt) {
#pragma unroll
        for (int i = 0; i < 4; ++i) {
          int n = mt * 16 + g * 4 + i;
          if (n < 49) outf[n * 128 + ((q ^ (n & 7)) << 2) + c3] = acc[mt][i] + bp;
        }
      }
    }
    __syncthreads();
#pragma unroll
    for (int it = 0; it < 7; ++it) {
      int f = it * 256 + tid;
      if (f < 1568) {
        int n = f >> 5, q2 = f & 31;
        outw4[n * 64 + half * 32 + q2] = outf4[n * 32 + (q2 ^ (n & 7))];
      }
    }
    __syncthreads();
  }
}

extern "C" void kernel_launch(void* const* d_in, const int* in_sizes, int n_in,
                              void* d_out, int out_size, void* d_ws, size_t ws_size,
                              hipStream_t stream) {
  const float* x = (const float*)d_in[0];
  const float* mask = (const float*)d_in[1];
  const float* w_qkv = (const float*)d_in[2];
  const float* b_qkv = (const float*)d_in[3];
  const float* w_proj = (const float*)d_in[4];
  const float* b_proj = (const float*)d_in[5];
  const float* bias_table = (const float*)d_in[6];
  const int* rel_index = (const int*)d_in[7];
  float* out = (float*)d_out;
  char* ws = (char*)d_ws;

  (void)in_sizes; (void)n_in; (void)out_size; (void)ws_size;

  hipFuncSetAttribute((const void*)attn_kernel, hipFuncAttributeMaxDynamicSharedMemorySize,
                      LDS_BYTES);

  prep_kernel<<<1103, 256, 0, stream>>>(w_qkv, b_qkv, w_proj, bias_table, rel_index, ws);
  attn_kernel<<<4096, 256, LDS_BYTES, stream>>>(x, mask, b_proj, ws, out);
}